// Round 1
// baseline (1171.505 us; speedup 1.0000x reference)
//
#include <hip/hip_runtime.h>
#include <cstdint>

// MoE grouped-GEMM pipeline for MI355X (gfx950).
//   T=4096 tokens, D=1024, H=5632, experts 0..3 active (4..7 masked), top-2.
// Phases (all on `stream`, stream-ordered):
//   memset cnt -> cvtx (x->bf16) -> gate (fp32 logits, top2, route) -> offsets
//   -> 3x transpose+cvt weights (fp32 [K][N] -> bf16 [N][K], experts 0..3)
//   -> gemm1 (x @ w1 & x @ w3, fused SwiGLU -> h bf16)
//   -> gemm2 (h @ w2, scaled by gate weight -> y bf16)
//   -> combine (out[t] = y[slot0] + y[slot1], fp32)
// Workspace layout (bytes), total 240,681,024 (yb aliases w1b, dead after gemm1):
//   xb 0 | w1b/yb 8388608 | w3b 54525952 | w2b 100663296 | hb 146800640 (8320 rows pad)
//   cnt 240517120 | offs 240517152 | perm 240517184 | wgt 240582720 | code 240648256

#define T_TOK 4096
#define DIM   1024
#define HID   5632
#define EA    4

typedef __bf16 bf16x8 __attribute__((ext_vector_type(8)));
typedef float  f32x4  __attribute__((ext_vector_type(4)));

__device__ __forceinline__ unsigned short f2b(float f) {
  union { float f; uint32_t u; } v; v.f = f;
  uint32_t r = v.u + 0x7fffu + ((v.u >> 16) & 1u);   // RNE, matches HW cvt
  return (unsigned short)(r >> 16);
}
__device__ __forceinline__ float b2f(unsigned short u) {
  union { uint32_t u; float f; } v; v.u = ((uint32_t)u) << 16;
  return v.f;
}
// async global->LDS, 16B per lane; LDS dest = wave-uniform base + lane*16
__device__ __forceinline__ void async16(const void* g, void* l) {
  __builtin_amdgcn_global_load_lds((const __attribute__((address_space(1))) void*)g,
                                   (__attribute__((address_space(3))) void*)l,
                                   16, 0, 0);
}

// ---------------- x fp32 -> bf16 ----------------
__global__ void cvtx_kernel(const float* __restrict__ x, unsigned short* __restrict__ xb) {
  const int i = blockIdx.x * blockDim.x + threadIdx.x;
  const float4 v = ((const float4*)x)[i];
  ushort4 o;
  o.x = f2b(v.x); o.y = f2b(v.y); o.z = f2b(v.z); o.w = f2b(v.w);
  ((ushort4*)xb)[i] = o;
}

// ---------------- gating: fp32 logits (experts 0..3), top-2, route ----------------
__global__ void gate_kernel(const float* __restrict__ x, const float* __restrict__ gw,
                            int* __restrict__ cnt, int* __restrict__ perm,
                            float* __restrict__ wgt, int* __restrict__ code) {
  const int lane = threadIdx.x & 63;
  const int wave = threadIdx.x >> 6;
  const int t = blockIdx.x * 4 + wave;          // one wave per token
  const float4* xv = (const float4*)(x + (size_t)t * DIM);
  const float4* g0 = (const float4*)gw;
  const float4* g1 = (const float4*)(gw + DIM);
  const float4* g2 = (const float4*)(gw + 2 * DIM);
  const float4* g3 = (const float4*)(gw + 3 * DIM);
  float a0 = 0.f, a1 = 0.f, a2 = 0.f, a3 = 0.f;
#pragma unroll
  for (int i = 0; i < 4; i++) {
    const int idx = i * 64 + lane;
    const float4 v = xv[idx];
    float4 w;
    w = g0[idx]; a0 += v.x*w.x + v.y*w.y + v.z*w.z + v.w*w.w;
    w = g1[idx]; a1 += v.x*w.x + v.y*w.y + v.z*w.z + v.w*w.w;
    w = g2[idx]; a2 += v.x*w.x + v.y*w.y + v.z*w.z + v.w*w.w;
    w = g3[idx]; a3 += v.x*w.x + v.y*w.y + v.z*w.z + v.w*w.w;
  }
#pragma unroll
  for (int off = 32; off > 0; off >>= 1) {
    a0 += __shfl_xor(a0, off);
    a1 += __shfl_xor(a1, off);
    a2 += __shfl_xor(a2, off);
    a3 += __shfl_xor(a3, off);
  }
  if (lane == 0) {
    float l[4] = {a0, a1, a2, a3};
    int a = 0;
#pragma unroll
    for (int e = 1; e < 4; e++) if (l[e] > l[a]) a = e;   // ties -> lower index (jax top_k)
    int b = (a == 0) ? 1 : 0;
#pragma unroll
    for (int e = 0; e < 4; e++) if (e != a && l[e] > l[b]) b = e;
    // softmax(top2) renormalized == sigmoid of logit gap
    const float wa = 1.0f / (1.0f + __expf(l[b] - l[a]));
    const float wb = 1.0f - wa;
    const int pa = atomicAdd(&cnt[a], 1);
    const int pb = atomicAdd(&cnt[b], 1);
    perm[a * T_TOK + pa] = t;  wgt[a * T_TOK + pa] = wa;  code[t * 2 + 0] = a * T_TOK + pa;
    perm[b * T_TOK + pb] = t;  wgt[b * T_TOK + pb] = wb;  code[t * 2 + 1] = b * T_TOK + pb;
  }
}

__global__ void offsets_kernel(const int* __restrict__ cnt, int* __restrict__ offs) {
  if (threadIdx.x == 0 && blockIdx.x == 0) {
    int s = 0;
#pragma unroll
    for (int e = 0; e < EA; e++) { offs[e] = s; s += cnt[e]; }
  }
}

// ---------------- per-expert transpose + fp32->bf16: in [R][C] -> out [C][R] ----------------
__global__ void tcvt_kernel(const float* __restrict__ in, unsigned short* __restrict__ out,
                            int R, int C) {
  __shared__ float tile[64][65];
  const size_t es = (size_t)R * C;
  const float* ip = in + (size_t)blockIdx.z * es;
  unsigned short* op = out + (size_t)blockIdx.z * es;
  const int bc = blockIdx.x * 64;
  const int br = blockIdx.y * 64;
  const int tr = threadIdx.x >> 4;
  const int tc = (threadIdx.x & 15) * 4;
#pragma unroll
  for (int i = 0; i < 4; i++) {
    const float4 v = *(const float4*)(ip + (size_t)(br + tr + i * 16) * C + bc + tc);
    tile[tr + i * 16][tc + 0] = v.x;
    tile[tr + i * 16][tc + 1] = v.y;
    tile[tr + i * 16][tc + 2] = v.z;
    tile[tr + i * 16][tc + 3] = v.w;
  }
  __syncthreads();
#pragma unroll
  for (int i = 0; i < 4; i++) {
    const int n = bc + tr + i * 16;
    ushort4 o;
    o.x = f2b(tile[tc + 0][tr + i * 16]);
    o.y = f2b(tile[tc + 1][tr + i * 16]);
    o.z = f2b(tile[tc + 2][tr + i * 16]);
    o.w = f2b(tile[tc + 3][tr + i * 16]);
    *(ushort4*)(op + (size_t)n * R + br + tc) = o;
  }
}

// ---------------- GEMM1: h = silu(x@w1) * (x@w3), gathered rows, 128x128x32 tiles ----------------
__global__ __launch_bounds__(256, 2)
void gemm1_kernel(const unsigned short* __restrict__ xb,
                  const unsigned short* __restrict__ w1b,
                  const unsigned short* __restrict__ w3b,
                  unsigned short* __restrict__ hb,
                  const int* __restrict__ cnt, const int* __restrict__ offs,
                  const int* __restrict__ perm) {
  const int e  = blockIdx.z;
  const int Me = cnt[e];
  const int m0 = blockIdx.x * 128;
  if (m0 >= Me) return;
  const int n0 = blockIdx.y * 128;
  const int goff = offs[e];
  const int tid = threadIdx.x, lane = tid & 63, wave = tid >> 6;

  __shared__ __align__(16) unsigned short As [128 * 32];  // [m][k]
  __shared__ __align__(16) unsigned short B1s[128 * 32];  // [n][k]
  __shared__ __align__(16) unsigned short B3s[128 * 32];

  // staging: 8 chunks/tile of 64 lanes x 16B; wave w stages chunks w and w+4
  const int c1 = wave, c2 = wave + 4;
  const int r1 = c1 * 16 + (lane >> 2);
  const int r2 = c2 * 16 + (lane >> 2);
  const int ks = (lane & 3) * 8;
  const int tok1 = perm[e * T_TOK + min(m0 + r1, Me - 1)];
  const int tok2 = perm[e * T_TOK + min(m0 + r2, Me - 1)];
  const unsigned short* gA1  = xb  + (size_t)tok1 * DIM + ks;
  const unsigned short* gA2  = xb  + (size_t)tok2 * DIM + ks;
  const unsigned short* gB11 = w1b + ((size_t)e * HID + n0 + r1) * DIM + ks;
  const unsigned short* gB12 = w1b + ((size_t)e * HID + n0 + r2) * DIM + ks;
  const unsigned short* gB31 = w3b + ((size_t)e * HID + n0 + r1) * DIM + ks;
  const unsigned short* gB32 = w3b + ((size_t)e * HID + n0 + r2) * DIM + ks;
  unsigned short* lA1  = As  + c1 * 512;
  unsigned short* lA2  = As  + c2 * 512;
  unsigned short* lB11 = B1s + c1 * 512;
  unsigned short* lB12 = B1s + c2 * 512;
  unsigned short* lB31 = B3s + c1 * 512;
  unsigned short* lB32 = B3s + c2 * 512;

  const int wm = wave >> 1, wn = wave & 1;       // 2x2 waves of 64x64
  const int fm = lane & 15;
  const int fk = (lane >> 4) * 8;
  const int aoff = (wm * 64 + fm) * 32 + fk;
  const int boff = (wn * 64 + fm) * 32 + fk;

  f32x4 acc1[4][4] = {};
  f32x4 acc3[4][4] = {};

  for (int k0 = 0; k0 < DIM; k0 += 32) {
    async16(gA1, lA1);   async16(gA2, lA2);
    async16(gB11, lB11); async16(gB12, lB12);
    async16(gB31, lB31); async16(gB32, lB32);
    gA1 += 32; gA2 += 32; gB11 += 32; gB12 += 32; gB31 += 32; gB32 += 32;
    __syncthreads();
    bf16x8 af[4], b1f[4], b3f[4];
#pragma unroll
    for (int i = 0; i < 4; i++) {
      af[i]  = *(const bf16x8*)(As  + aoff + i * 512);
      b1f[i] = *(const bf16x8*)(B1s + boff + i * 512);
      b3f[i] = *(const bf16x8*)(B3s + boff + i * 512);
    }
#pragma unroll
    for (int mi = 0; mi < 4; mi++)
#pragma unroll
      for (int ni = 0; ni < 4; ni++) {
        acc1[mi][ni] = __builtin_amdgcn_mfma_f32_16x16x32_bf16(af[mi], b1f[ni], acc1[mi][ni], 0, 0, 0);
        acc3[mi][ni] = __builtin_amdgcn_mfma_f32_16x16x32_bf16(af[mi], b3f[ni], acc3[mi][ni], 0, 0, 0);
      }
    __syncthreads();
  }
  // epilogue: SwiGLU, masked store (C/D layout: col=lane&15, row=(lane>>4)*4+reg)
#pragma unroll
  for (int mi = 0; mi < 4; mi++) {
#pragma unroll
    for (int r = 0; r < 4; r++) {
      const int m = m0 + wm * 64 + mi * 16 + (lane >> 4) * 4 + r;
      if (m < Me) {
        unsigned short* hp = hb + (size_t)(goff + m) * HID + n0 + wn * 64 + fm;
#pragma unroll
        for (int ni = 0; ni < 4; ni++) {
          const float a = acc1[mi][ni][r];
          const float g = acc3[mi][ni][r];
          const float s = a / (1.0f + __expf(-a));
          hp[ni * 16] = f2b(s * g);
        }
      }
    }
  }
}

// ---------------- GEMM2: y = (h @ w2) * gate_w, 128x128x32 tiles over K=5632 ----------------
__global__ __launch_bounds__(256, 2)
void gemm2_kernel(const unsigned short* __restrict__ hb,
                  const unsigned short* __restrict__ w2b,
                  unsigned short* __restrict__ yb,
                  const int* __restrict__ cnt, const int* __restrict__ offs,
                  const float* __restrict__ wgt) {
  const int e  = blockIdx.z;
  const int Me = cnt[e];
  const int m0 = blockIdx.x * 128;
  if (m0 >= Me) return;
  const int n0 = blockIdx.y * 128;
  const int goff = offs[e];
  const int tid = threadIdx.x, lane = tid & 63, wave = tid >> 6;

  __shared__ __align__(16) unsigned short As[128 * 32];
  __shared__ __align__(16) unsigned short Bs[128 * 32];

  const int c1 = wave, c2 = wave + 4;
  const int r1 = c1 * 16 + (lane >> 2);
  const int r2 = c2 * 16 + (lane >> 2);
  const int ks = (lane & 3) * 8;
  const unsigned short* gA1 = hb  + (size_t)(goff + m0 + r1) * HID + ks; // overreads hit pad rows
  const unsigned short* gA2 = hb  + (size_t)(goff + m0 + r2) * HID + ks;
  const unsigned short* gB1 = w2b + ((size_t)e * DIM + n0 + r1) * HID + ks;
  const unsigned short* gB2 = w2b + ((size_t)e * DIM + n0 + r2) * HID + ks;
  unsigned short* lA1 = As + c1 * 512;
  unsigned short* lA2 = As + c2 * 512;
  unsigned short* lB1 = Bs + c1 * 512;
  unsigned short* lB2 = Bs + c2 * 512;

  const int wm = wave >> 1, wn = wave & 1;
  const int fm = lane & 15, fk = (lane >> 4) * 8;
  const int aoff = (wm * 64 + fm) * 32 + fk;
  const int boff = (wn * 64 + fm) * 32 + fk;

  f32x4 acc[4][4] = {};
  for (int k0 = 0; k0 < HID; k0 += 32) {
    async16(gA1, lA1); async16(gA2, lA2);
    async16(gB1, lB1); async16(gB2, lB2);
    gA1 += 32; gA2 += 32; gB1 += 32; gB2 += 32;
    __syncthreads();
    bf16x8 af[4], bfr[4];
#pragma unroll
    for (int i = 0; i < 4; i++) {
      af[i]  = *(const bf16x8*)(As + aoff + i * 512);
      bfr[i] = *(const bf16x8*)(Bs + boff + i * 512);
    }
#pragma unroll
    for (int mi = 0; mi < 4; mi++)
#pragma unroll
      for (int ni = 0; ni < 4; ni++)
        acc[mi][ni] = __builtin_amdgcn_mfma_f32_16x16x32_bf16(af[mi], bfr[ni], acc[mi][ni], 0, 0, 0);
    __syncthreads();
  }
#pragma unroll
  for (int mi = 0; mi < 4; mi++) {
#pragma unroll
    for (int r = 0; r < 4; r++) {
      const int m = m0 + wm * 64 + mi * 16 + (lane >> 4) * 4 + r;
      if (m < Me) {
        const float gwv = wgt[e * T_TOK + m];
        unsigned short* yp = yb + (size_t)(goff + m) * DIM + n0 + wn * 64 + fm;
#pragma unroll
        for (int ni = 0; ni < 4; ni++)
          yp[ni * 16] = f2b(acc[mi][ni][r] * gwv);
      }
    }
  }
}

// ---------------- combine: out[t] = y[slot0(t)] + y[slot1(t)] ----------------
__global__ void combine_kernel(const unsigned short* __restrict__ yb,
                               const int* __restrict__ code,
                               const int* __restrict__ offs,
                               float* __restrict__ out) {
  const int t = blockIdx.x;
  const int d = threadIdx.x * 4;
  const int c0 = code[t * 2 + 0];
  const int c1 = code[t * 2 + 1];
  const size_t g0 = ((size_t)(offs[c0 >> 12] + (c0 & 4095))) * DIM + d;
  const size_t g1 = ((size_t)(offs[c1 >> 12] + (c1 & 4095))) * DIM + d;
  const ushort4 y0 = *(const ushort4*)(yb + g0);
  const ushort4 y1 = *(const ushort4*)(yb + g1);
  float4 o;
  o.x = b2f(y0.x) + b2f(y1.x);
  o.y = b2f(y0.y) + b2f(y1.y);
  o.z = b2f(y0.z) + b2f(y1.z);
  o.w = b2f(y0.w) + b2f(y1.w);
  *(float4*)(out + (size_t)t * DIM + d) = o;
}

extern "C" void kernel_launch(void* const* d_in, const int* in_sizes, int n_in,
                              void* d_out, int out_size, void* d_ws, size_t ws_size,
                              hipStream_t stream) {
  (void)in_sizes; (void)n_in; (void)out_size; (void)ws_size;
  const float* x  = (const float*)d_in[0];
  const float* gw = (const float*)d_in[1];
  const float* w1 = (const float*)d_in[2];   // [E][D][H]
  const float* w2 = (const float*)d_in[3];   // [E][H][D]  (dict order: w2 before w3!)
  const float* w3 = (const float*)d_in[4];   // [E][D][H]
  float* out = (float*)d_out;
  char* ws = (char*)d_ws;

  unsigned short* xb  = (unsigned short*)(ws + 0);
  unsigned short* w1b = (unsigned short*)(ws + 8388608);
  unsigned short* yb  = (unsigned short*)(ws + 8388608);    // aliases w1b (dead after gemm1)
  unsigned short* w3b = (unsigned short*)(ws + 54525952);
  unsigned short* w2b = (unsigned short*)(ws + 100663296);
  unsigned short* hb  = (unsigned short*)(ws + 146800640);  // 8320 rows x 5632 bf16 (128 pad rows)
  int*   cnt  = (int*)(ws + 240517120);
  int*   offs = (int*)(ws + 240517152);
  int*   perm = (int*)(ws + 240517184);
  float* wgt  = (float*)(ws + 240582720);
  int*   code = (int*)(ws + 240648256);
  // total workspace used: 240,681,024 bytes

  hipMemsetAsync(cnt, 0, EA * sizeof(int), stream);
  cvtx_kernel<<<4096, 256, 0, stream>>>(x, xb);
  gate_kernel<<<1024, 256, 0, stream>>>(x, gw, cnt, perm, wgt, code);
  offsets_kernel<<<1, 64, 0, stream>>>(cnt, offs);
  tcvt_kernel<<<dim3(88, 16, EA), 256, 0, stream>>>(w1, w1b, DIM, HID);  // -> [e][H][D]
  tcvt_kernel<<<dim3(88, 16, EA), 256, 0, stream>>>(w3, w3b, DIM, HID);  // -> [e][H][D]
  tcvt_kernel<<<dim3(16, 88, EA), 256, 0, stream>>>(w2, w2b, HID, DIM);  // -> [e][D][H]
  gemm1_kernel<<<dim3(32, 44, EA), 256, 0, stream>>>(xb, w1b, w3b, hb, cnt, offs, perm);
  gemm2_kernel<<<dim3(32, 8, EA), 256, 0, stream>>>(hb, w2b, yb, cnt, offs, wgt);
  combine_kernel<<<4096, 256, 0, stream>>>(yb, code, offs, out);
}

// Round 2
// 956.157 us; speedup vs baseline: 1.2252x; 1.2252x over previous
//
#include <hip/hip_runtime.h>
#include <cstdint>

// MoE grouped-GEMM pipeline for MI355X (gfx950).
//   T=4096 tokens, D=1024, H=5632, experts 0..3 active (4..7 masked), top-2.
// R2: ping-pong LDS double-buffer K-loops with raw s_barrier + explicit
//     s_waitcnt vmcnt(N) (prefetch stays in flight across barrier), and
//     XCD-swizzled 1-D grids (same-(e,n) m-blocks at stride % 8 == 0).
// Workspace layout (bytes), total 240,681,024 (yb aliases w1b, dead after gemm1):
//   xb 0 | w1b/yb 8388608 | w3b 54525952 | w2b 100663296 | hb 146800640 (8320 rows pad)
//   cnt 240517120 | offs 240517152 | perm 240517184 | wgt 240582720 | code 240648256

#define T_TOK 4096
#define DIM   1024
#define HID   5632
#define EA    4

typedef __bf16 bf16x8 __attribute__((ext_vector_type(8)));
typedef float  f32x4  __attribute__((ext_vector_type(4)));

__device__ __forceinline__ unsigned short f2b(float f) {
  union { float f; uint32_t u; } v; v.f = f;
  uint32_t r = v.u + 0x7fffu + ((v.u >> 16) & 1u);   // RNE, matches HW cvt
  return (unsigned short)(r >> 16);
}
__device__ __forceinline__ float b2f(unsigned short u) {
  union { uint32_t u; float f; } v; v.u = ((uint32_t)u) << 16;
  return v.f;
}
// async global->LDS, 16B per lane; LDS dest = wave-uniform base + lane*16
__device__ __forceinline__ void async16(const void* g, void* l) {
  __builtin_amdgcn_global_load_lds((const __attribute__((address_space(1))) void*)g,
                                   (__attribute__((address_space(3))) void*)l,
                                   16, 0, 0);
}
// raw sync primitives: keep prefetch loads in flight across the barrier
__device__ __forceinline__ void bar_raw()   { asm volatile("s_barrier" ::: "memory"); }
__device__ __forceinline__ void wait_vm6()  { asm volatile("s_waitcnt vmcnt(6)" ::: "memory"); }
__device__ __forceinline__ void wait_vm4()  { asm volatile("s_waitcnt vmcnt(4)" ::: "memory"); }
__device__ __forceinline__ void wait_vm0()  { asm volatile("s_waitcnt vmcnt(0)" ::: "memory"); }
__device__ __forceinline__ void wait_lgkm0(){ asm volatile("s_waitcnt lgkmcnt(0)" ::: "memory"); }

// ---------------- x fp32 -> bf16 ----------------
__global__ void cvtx_kernel(const float* __restrict__ x, unsigned short* __restrict__ xb) {
  const int i = blockIdx.x * blockDim.x + threadIdx.x;
  const float4 v = ((const float4*)x)[i];
  ushort4 o;
  o.x = f2b(v.x); o.y = f2b(v.y); o.z = f2b(v.z); o.w = f2b(v.w);
  ((ushort4*)xb)[i] = o;
}

// ---------------- gating: fp32 logits (experts 0..3), top-2, route ----------------
__global__ void gate_kernel(const float* __restrict__ x, const float* __restrict__ gw,
                            int* __restrict__ cnt, int* __restrict__ perm,
                            float* __restrict__ wgt, int* __restrict__ code) {
  const int lane = threadIdx.x & 63;
  const int wave = threadIdx.x >> 6;
  const int t = blockIdx.x * 4 + wave;          // one wave per token
  const float4* xv = (const float4*)(x + (size_t)t * DIM);
  const float4* g0 = (const float4*)gw;
  const float4* g1 = (const float4*)(gw + DIM);
  const float4* g2 = (const float4*)(gw + 2 * DIM);
  const float4* g3 = (const float4*)(gw + 3 * DIM);
  float a0 = 0.f, a1 = 0.f, a2 = 0.f, a3 = 0.f;
#pragma unroll
  for (int i = 0; i < 4; i++) {
    const int idx = i * 64 + lane;
    const float4 v = xv[idx];
    float4 w;
    w = g0[idx]; a0 += v.x*w.x + v.y*w.y + v.z*w.z + v.w*w.w;
    w = g1[idx]; a1 += v.x*w.x + v.y*w.y + v.z*w.z + v.w*w.w;
    w = g2[idx]; a2 += v.x*w.x + v.y*w.y + v.z*w.z + v.w*w.w;
    w = g3[idx]; a3 += v.x*w.x + v.y*w.y + v.z*w.z + v.w*w.w;
  }
#pragma unroll
  for (int off = 32; off > 0; off >>= 1) {
    a0 += __shfl_xor(a0, off);
    a1 += __shfl_xor(a1, off);
    a2 += __shfl_xor(a2, off);
    a3 += __shfl_xor(a3, off);
  }
  if (lane == 0) {
    float l[4] = {a0, a1, a2, a3};
    int a = 0;
#pragma unroll
    for (int e = 1; e < 4; e++) if (l[e] > l[a]) a = e;   // ties -> lower index (jax top_k)
    int b = (a == 0) ? 1 : 0;
#pragma unroll
    for (int e = 0; e < 4; e++) if (e != a && l[e] > l[b]) b = e;
    // softmax(top2) renormalized == sigmoid of logit gap
    const float wa = 1.0f / (1.0f + __expf(l[b] - l[a]));
    const float wb = 1.0f - wa;
    const int pa = atomicAdd(&cnt[a], 1);
    const int pb = atomicAdd(&cnt[b], 1);
    perm[a * T_TOK + pa] = t;  wgt[a * T_TOK + pa] = wa;  code[t * 2 + 0] = a * T_TOK + pa;
    perm[b * T_TOK + pb] = t;  wgt[b * T_TOK + pb] = wb;  code[t * 2 + 1] = b * T_TOK + pb;
  }
}

__global__ void offsets_kernel(const int* __restrict__ cnt, int* __restrict__ offs) {
  if (threadIdx.x == 0 && blockIdx.x == 0) {
    int s = 0;
#pragma unroll
    for (int e = 0; e < EA; e++) { offs[e] = s; s += cnt[e]; }
  }
}

// ---------------- per-expert transpose + fp32->bf16: in [R][C] -> out [C][R] ----------------
__global__ void tcvt_kernel(const float* __restrict__ in, unsigned short* __restrict__ out,
                            int R, int C) {
  __shared__ float tile[64][65];
  const size_t es = (size_t)R * C;
  const float* ip = in + (size_t)blockIdx.z * es;
  unsigned short* op = out + (size_t)blockIdx.z * es;
  const int bc = blockIdx.x * 64;
  const int br = blockIdx.y * 64;
  const int tr = threadIdx.x >> 4;
  const int tc = (threadIdx.x & 15) * 4;
#pragma unroll
  for (int i = 0; i < 4; i++) {
    const float4 v = *(const float4*)(ip + (size_t)(br + tr + i * 16) * C + bc + tc);
    tile[tr + i * 16][tc + 0] = v.x;
    tile[tr + i * 16][tc + 1] = v.y;
    tile[tr + i * 16][tc + 2] = v.z;
    tile[tr + i * 16][tc + 3] = v.w;
  }
  __syncthreads();
#pragma unroll
  for (int i = 0; i < 4; i++) {
    const int n = bc + tr + i * 16;
    ushort4 o;
    o.x = f2b(tile[tc + 0][tr + i * 16]);
    o.y = f2b(tile[tc + 1][tr + i * 16]);
    o.z = f2b(tile[tc + 2][tr + i * 16]);
    o.w = f2b(tile[tc + 3][tr + i * 16]);
    *(ushort4*)(op + (size_t)n * R + br + tc) = o;
  }
}

// ---------------- GEMM1: h = silu(x@w1) * (x@w3), dbuf pipeline ----------------
// 1-D grid 5632: n fastest (44), then e (4), then m (32); same-(e,n) stride 176 % 8 == 0.
__global__ __launch_bounds__(256, 2)
void gemm1_kernel(const unsigned short* __restrict__ xb,
                  const unsigned short* __restrict__ w1b,
                  const unsigned short* __restrict__ w3b,
                  unsigned short* __restrict__ hb,
                  const int* __restrict__ cnt, const int* __restrict__ offs,
                  const int* __restrict__ perm) {
  const int id = blockIdx.x;
  const int nb = id % 44;
  const int e  = (id / 44) % 4;
  const int mb = id / 176;
  const int Me = cnt[e];
  const int m0 = mb * 128;
  if (m0 >= Me) return;
  const int n0 = nb * 128;
  const int goff = offs[e];
  const int tid = threadIdx.x, lane = tid & 63, wave = tid >> 6;

  // ping-pong: buf b at b*12288 shorts; A +0, B1 +4096, B3 +8192
  __shared__ __align__(16) unsigned short lds[2 * 12288];

  const int c1 = wave, c2 = wave + 4;          // two 16-row chunks per wave
  const int r1 = c1 * 16 + (lane >> 2);
  const int r2 = c2 * 16 + (lane >> 2);
  const int ks = (lane & 3) * 8;
  const int tok1 = perm[e * T_TOK + min(m0 + r1, Me - 1)];
  const int tok2 = perm[e * T_TOK + min(m0 + r2, Me - 1)];
  const unsigned short* gA1  = xb  + (size_t)tok1 * DIM + ks;
  const unsigned short* gA2  = xb  + (size_t)tok2 * DIM + ks;
  const unsigned short* gB11 = w1b + ((size_t)e * HID + n0 + r1) * DIM + ks;
  const unsigned short* gB12 = w1b + ((size_t)e * HID + n0 + r2) * DIM + ks;
  const unsigned short* gB31 = w3b + ((size_t)e * HID + n0 + r1) * DIM + ks;
  const unsigned short* gB32 = w3b + ((size_t)e * HID + n0 + r2) * DIM + ks;
  const int o1 = c1 * 512, o2 = c2 * 512;

  const int wm = wave >> 1, wn = wave & 1;     // 2x2 waves of 64x64
  const int fm = lane & 15;
  const int fk = (lane >> 4) * 8;
  const int aoff = (wm * 64 + fm) * 32 + fk;
  const int boff = (wn * 64 + fm) * 32 + fk;

  f32x4 acc1[4][4] = {};
  f32x4 acc3[4][4] = {};

  // preload tile 0 into buf 0
  {
    unsigned short* d = lds;
    async16(gA1,  d + o1);        async16(gA2,  d + o2);
    async16(gB11, d + 4096 + o1); async16(gB12, d + 4096 + o2);
    async16(gB31, d + 8192 + o1); async16(gB32, d + 8192 + o2);
    gA1 += 32; gA2 += 32; gB11 += 32; gB12 += 32; gB31 += 32; gB32 += 32;
  }
  for (int i = 0; i < 31; ++i) {
    // issue tile i+1 into the other buffer (in-bounds: k <= 992)
    unsigned short* d = lds + ((i + 1) & 1) * 12288;
    async16(gA1,  d + o1);        async16(gA2,  d + o2);
    async16(gB11, d + 4096 + o1); async16(gB12, d + 4096 + o2);
    async16(gB31, d + 8192 + o1); async16(gB32, d + 8192 + o2);
    gA1 += 32; gA2 += 32; gB11 += 32; gB12 += 32; gB31 += 32; gB32 += 32;
    wait_vm6();                       // tile i drained; tile i+1 still in flight
    bar_raw();
    const unsigned short* s = lds + (i & 1) * 12288;
    bf16x8 af[4], b1f[4], b3f[4];
#pragma unroll
    for (int j = 0; j < 4; j++) {
      af[j]  = *(const bf16x8*)(s + aoff + j * 512);
      b1f[j] = *(const bf16x8*)(s + 4096 + boff + j * 512);
      b3f[j] = *(const bf16x8*)(s + 8192 + boff + j * 512);
    }
    wait_lgkm0();                     // frags in registers
    bar_raw();                        // all waves done reading; buf reusable
#pragma unroll
    for (int mi = 0; mi < 4; mi++)
#pragma unroll
      for (int ni = 0; ni < 4; ni++) {
        acc1[mi][ni] = __builtin_amdgcn_mfma_f32_16x16x32_bf16(af[mi], b1f[ni], acc1[mi][ni], 0, 0, 0);
        acc3[mi][ni] = __builtin_amdgcn_mfma_f32_16x16x32_bf16(af[mi], b3f[ni], acc3[mi][ni], 0, 0, 0);
      }
  }
  // peeled last tile (buf 1)
  {
    wait_vm0();
    bar_raw();
    const unsigned short* s = lds + 12288;
    bf16x8 af[4], b1f[4], b3f[4];
#pragma unroll
    for (int j = 0; j < 4; j++) {
      af[j]  = *(const bf16x8*)(s + aoff + j * 512);
      b1f[j] = *(const bf16x8*)(s + 4096 + boff + j * 512);
      b3f[j] = *(const bf16x8*)(s + 8192 + boff + j * 512);
    }
#pragma unroll
    for (int mi = 0; mi < 4; mi++)
#pragma unroll
      for (int ni = 0; ni < 4; ni++) {
        acc1[mi][ni] = __builtin_amdgcn_mfma_f32_16x16x32_bf16(af[mi], b1f[ni], acc1[mi][ni], 0, 0, 0);
        acc3[mi][ni] = __builtin_amdgcn_mfma_f32_16x16x32_bf16(af[mi], b3f[ni], acc3[mi][ni], 0, 0, 0);
      }
  }
  // epilogue: SwiGLU, masked store (C/D layout: col=lane&15, row=(lane>>4)*4+reg)
#pragma unroll
  for (int mi = 0; mi < 4; mi++) {
#pragma unroll
    for (int r = 0; r < 4; r++) {
      const int m = m0 + wm * 64 + mi * 16 + (lane >> 4) * 4 + r;
      if (m < Me) {
        unsigned short* hp = hb + (size_t)(goff + m) * HID + n0 + wn * 64 + fm;
#pragma unroll
        for (int ni = 0; ni < 4; ni++) {
          const float a = acc1[mi][ni][r];
          const float g = acc3[mi][ni][r];
          const float s = a / (1.0f + __expf(-a));
          hp[ni * 16] = f2b(s * g);
        }
      }
    }
  }
}

// ---------------- GEMM2: y = (h @ w2) * gate_w, dbuf pipeline over K=5632 ----------------
// 1-D grid 1024: n fastest (8), then e (4), then m (32); same-(e,n) stride 32 % 8 == 0.
__global__ __launch_bounds__(256, 2)
void gemm2_kernel(const unsigned short* __restrict__ hb,
                  const unsigned short* __restrict__ w2b,
                  unsigned short* __restrict__ yb,
                  const int* __restrict__ cnt, const int* __restrict__ offs,
                  const float* __restrict__ wgt) {
  const int id = blockIdx.x;
  const int nb = id & 7;
  const int e  = (id >> 3) & 3;
  const int mb = id >> 5;
  const int Me = cnt[e];
  const int m0 = mb * 128;
  if (m0 >= Me) return;
  const int n0 = nb * 128;
  const int goff = offs[e];
  const int tid = threadIdx.x, lane = tid & 63, wave = tid >> 6;

  // ping-pong: buf b at b*8192 shorts; A +0, B +4096
  __shared__ __align__(16) unsigned short lds[2 * 8192];

  const int c1 = wave, c2 = wave + 4;
  const int r1 = c1 * 16 + (lane >> 2);
  const int r2 = c2 * 16 + (lane >> 2);
  const int ks = (lane & 3) * 8;
  const unsigned short* gA1 = hb  + (size_t)(goff + m0 + r1) * HID + ks; // overreads hit pad rows
  const unsigned short* gA2 = hb  + (size_t)(goff + m0 + r2) * HID + ks;
  const unsigned short* gB1 = w2b + ((size_t)e * DIM + n0 + r1) * HID + ks;
  const unsigned short* gB2 = w2b + ((size_t)e * DIM + n0 + r2) * HID + ks;
  const int o1 = c1 * 512, o2 = c2 * 512;

  const int wm = wave >> 1, wn = wave & 1;
  const int fm = lane & 15, fk = (lane >> 4) * 8;
  const int aoff = (wm * 64 + fm) * 32 + fk;
  const int boff = (wn * 64 + fm) * 32 + fk;

  f32x4 acc[4][4] = {};
  {
    unsigned short* d = lds;
    async16(gA1, d + o1); async16(gA2, d + o2);
    async16(gB1, d + 4096 + o1); async16(gB2, d + 4096 + o2);
    gA1 += 32; gA2 += 32; gB1 += 32; gB2 += 32;
  }
  for (int i = 0; i < 175; ++i) {
    unsigned short* d = lds + ((i + 1) & 1) * 8192;
    async16(gA1, d + o1); async16(gA2, d + o2);
    async16(gB1, d + 4096 + o1); async16(gB2, d + 4096 + o2);
    gA1 += 32; gA2 += 32; gB1 += 32; gB2 += 32;
    wait_vm4();
    bar_raw();
    const unsigned short* s = lds + (i & 1) * 8192;
    bf16x8 af[4], bfr[4];
#pragma unroll
    for (int j = 0; j < 4; j++) {
      af[j]  = *(const bf16x8*)(s + aoff + j * 512);
      bfr[j] = *(const bf16x8*)(s + 4096 + boff + j * 512);
    }
    wait_lgkm0();
    bar_raw();
#pragma unroll
    for (int mi = 0; mi < 4; mi++)
#pragma unroll
      for (int ni = 0; ni < 4; ni++)
        acc[mi][ni] = __builtin_amdgcn_mfma_f32_16x16x32_bf16(af[mi], bfr[ni], acc[mi][ni], 0, 0, 0);
  }
  {
    wait_vm0();
    bar_raw();
    const unsigned short* s = lds + 8192;
    bf16x8 af[4], bfr[4];
#pragma unroll
    for (int j = 0; j < 4; j++) {
      af[j]  = *(const bf16x8*)(s + aoff + j * 512);
      bfr[j] = *(const bf16x8*)(s + 4096 + boff + j * 512);
    }
#pragma unroll
    for (int mi = 0; mi < 4; mi++)
#pragma unroll
      for (int ni = 0; ni < 4; ni++)
        acc[mi][ni] = __builtin_amdgcn_mfma_f32_16x16x32_bf16(af[mi], bfr[ni], acc[mi][ni], 0, 0, 0);
  }
#pragma unroll
  for (int mi = 0; mi < 4; mi++) {
#pragma unroll
    for (int r = 0; r < 4; r++) {
      const int m = m0 + wm * 64 + mi * 16 + (lane >> 4) * 4 + r;
      if (m < Me) {
        const float gwv = wgt[e * T_TOK + m];
        unsigned short* yp = yb + (size_t)(goff + m) * DIM + n0 + wn * 64 + fm;
#pragma unroll
        for (int ni = 0; ni < 4; ni++)
          yp[ni * 16] = f2b(acc[mi][ni][r] * gwv);
      }
    }
  }
}

// ---------------- combine: out[t] = y[slot0(t)] + y[slot1(t)] ----------------
__global__ void combine_kernel(const unsigned short* __restrict__ yb,
                               const int* __restrict__ code,
                               const int* __restrict__ offs,
                               float* __restrict__ out) {
  const int t = blockIdx.x;
  const int d = threadIdx.x * 4;
  const int c0 = code[t * 2 + 0];
  const int c1 = code[t * 2 + 1];
  const size_t g0 = ((size_t)(offs[c0 >> 12] + (c0 & 4095))) * DIM + d;
  const size_t g1 = ((size_t)(offs[c1 >> 12] + (c1 & 4095))) * DIM + d;
  const ushort4 y0 = *(const ushort4*)(yb + g0);
  const ushort4 y1 = *(const ushort4*)(yb + g1);
  float4 o;
  o.x = b2f(y0.x) + b2f(y1.x);
  o.y = b2f(y0.y) + b2f(y1.y);
  o.z = b2f(y0.z) + b2f(y1.z);
  o.w = b2f(y0.w) + b2f(y1.w);
  *(float4*)(out + (size_t)t * DIM + d) = o;
}

extern "C" void kernel_launch(void* const* d_in, const int* in_sizes, int n_in,
                              void* d_out, int out_size, void* d_ws, size_t ws_size,
                              hipStream_t stream) {
  (void)in_sizes; (void)n_in; (void)out_size; (void)ws_size;
  const float* x  = (const float*)d_in[0];
  const float* gw = (const float*)d_in[1];
  const float* w1 = (const float*)d_in[2];   // [E][D][H]
  const float* w2 = (const float*)d_in[3];   // [E][H][D]  (dict order: w2 before w3!)
  const float* w3 = (const float*)d_in[4];   // [E][D][H]
  float* out = (float*)d_out;
  char* ws = (char*)d_ws;

  unsigned short* xb  = (unsigned short*)(ws + 0);
  unsigned short* w1b = (unsigned short*)(ws + 8388608);
  unsigned short* yb  = (unsigned short*)(ws + 8388608);    // aliases w1b (dead after gemm1)
  unsigned short* w3b = (unsigned short*)(ws + 54525952);
  unsigned short* w2b = (unsigned short*)(ws + 100663296);
  unsigned short* hb  = (unsigned short*)(ws + 146800640);  // 8320 rows x 5632 bf16 (128 pad rows)
  int*   cnt  = (int*)(ws + 240517120);
  int*   offs = (int*)(ws + 240517152);
  int*   perm = (int*)(ws + 240517184);
  float* wgt  = (float*)(ws + 240582720);
  int*   code = (int*)(ws + 240648256);

  hipMemsetAsync(cnt, 0, EA * sizeof(int), stream);
  cvtx_kernel<<<4096, 256, 0, stream>>>(x, xb);
  gate_kernel<<<1024, 256, 0, stream>>>(x, gw, cnt, perm, wgt, code);
  offsets_kernel<<<1, 64, 0, stream>>>(cnt, offs);
  tcvt_kernel<<<dim3(88, 16, EA), 256, 0, stream>>>(w1, w1b, DIM, HID);  // -> [e][H][D]
  tcvt_kernel<<<dim3(88, 16, EA), 256, 0, stream>>>(w3, w3b, DIM, HID);  // -> [e][H][D]
  tcvt_kernel<<<dim3(16, 88, EA), 256, 0, stream>>>(w2, w2b, HID, DIM);  // -> [e][D][H]
  gemm1_kernel<<<5632, 256, 0, stream>>>(xb, w1b, w3b, hb, cnt, offs, perm);
  gemm2_kernel<<<1024, 256, 0, stream>>>(hb, w2b, yb, cnt, offs, wgt);
  combine_kernel<<<4096, 256, 0, stream>>>(yb, code, offs, out);
}